// Round 7
// baseline (118.429 us; speedup 1.0000x reference)
//
#include <hip/hip_runtime.h>
#include <hip/hip_bf16.h>

// QConv1d: x (8,64,16384) f32, w (64,64,9) f32, bias (64) f32
// out (8,64,16384) f32 = conv1d(x, w, pad=4) * 0.125 + bias
// Round-12: DECOMPOSITION MEASUREMENT. Kernel body is byte-identical to
// round-7 (measured best, 98.0 µs). kernel_launch dispatches qconv TWICE:
// the second dispatch is idempotent (same inputs -> same output), and its
// marginal cost on dur_us measures the true qconv body time (L3-warm).
//   dur ~108-113  => body ~10-15 µs => kernel at pipe floor, window is
//                    harness-dominated => roofline.
//   dur ~125-150  => body ~27-50 µs => kernel far off floor, bottleneck is
//                    not cold-HBM => attack scheduling next round.
#define C_IN    64
#define L_IN    16384
#define O_OUT   64
#define KTAP    9
#define LTILE   256
#define ROWS    272      // LTILE + 16 halo rows (global l in [l0-8, l0+264))
#define RSTRIDE 72       // 64 + 8 pad (multiple of 8 -> 16B-aligned b128 rows)

typedef short          bf16x8 __attribute__((ext_vector_type(8)));   // MFMA A/B frag
typedef unsigned int   u32x4  __attribute__((ext_vector_type(4)));
typedef float          f32x4  __attribute__((ext_vector_type(4)));   // MFMA C/D frag

static __device__ __forceinline__ unsigned short f2bf(float f) {
  __hip_bfloat16 h = __float2bfloat16(f);   // round-to-nearest
  return __builtin_bit_cast(unsigned short, h);
}

// pack two floats -> one u32 of two bf16 (lo in low 16 bits)
static __device__ __forceinline__ unsigned int pk2(float lo, float hi) {
  return (unsigned int)f2bf(lo) | ((unsigned int)f2bf(hi) << 16);
}

// ---------------------------------------------------------------------------
// Pre-kernel: w[o][c][t] fp32 (stride-9 taps) -> W2[t][o][c] bf16 (c contig),
// pre-scaled by 0.125 (exact: power-of-two only touches the exponent).
// ---------------------------------------------------------------------------
__global__ void w_rearrange(const float* __restrict__ w,
                            unsigned short* __restrict__ w2) {
    int i = blockIdx.x * 256 + threadIdx.x;       // i = t*4096 + o*64 + c
    if (i >= KTAP * O_OUT * C_IN) return;
    int t  = i >> 12;
    int oc = i & 4095;                            // o*64 + c
    w2[i] = f2bf(w[oc * KTAP + t] * 0.125f);
}

// ---------------------------------------------------------------------------
// Main kernel: one block = one n, one 256-wide L tile, all 64 outputs.
// 4 waves, each owning 16 O rows; the two 128-wide L halves are computed
// sequentially with memory traffic overlapped against MFMA.
// ---------------------------------------------------------------------------
__global__ __launch_bounds__(256) void qconv_kernel(
    const float* __restrict__ x,
    const unsigned short* __restrict__ w2,    // bf16 bits, pre-scaled
    const float* __restrict__ bias,
    float* __restrict__ out) {

  __shared__ __align__(16) unsigned short xs[ROWS][RSTRIDE];  // bf16 x tile, [l][c]

  const int tid = threadIdx.x;
  const int n   = blockIdx.x >> 6;
  const int l0  = (blockIdx.x & 63) << 8;      // tile base along L
  const float* xn = x + (size_t)n * C_IN * L_IN;

  // ---- Issue phase: all global loads for this tile ----------------------
  const int ucb = tid & 7;            // channel block (c0 = ucb*8)
  const int ulb = tid >> 3;           // l block within region (0..31)
  const int uc0 = ucb << 3;

  // A unit 0 (rows ulb*4 .. +3)
  const int a0_gl0 = l0 - 8 + (ulb << 2);
  const bool a0_ok = (a0_gl0 >= 0) && (a0_gl0 + 4 <= L_IN);
  f32x4 va0[8];
  if (a0_ok) {
#pragma unroll
    for (int i = 0; i < 8; ++i)
      va0[i] = *reinterpret_cast<const f32x4*>(xn + (size_t)(uc0 + i) * L_IN + a0_gl0);
  }
  // A unit 1 (tid < 32): rows 128 + (tid>>3)*4 .. +3  — always in-bounds
  const bool have1 = (tid < 32);
  const int a1_gl0 = l0 - 8 + ((32 + ulb) << 2);   // only meaningful for tid<32
  f32x4 va1[8];
  if (have1) {
#pragma unroll
    for (int i = 0; i < 8; ++i)
      va1[i] = *reinterpret_cast<const f32x4*>(xn + (size_t)(uc0 + i) * L_IN + a1_gl0);
  }
  // B unit: rows 144 + ulb*4 .. +3 (gl0 >= 136 >= 0 always)
  const int b_gl0 = l0 + 136 + (ulb << 2);
  const bool b_ok = (b_gl0 + 4 <= L_IN);
  f32x4 vb[8];
  if (b_ok) {
#pragma unroll
    for (int i = 0; i < 8; ++i)
      vb[i] = *reinterpret_cast<const f32x4*>(xn + (size_t)(uc0 + i) * L_IN + b_gl0);
  }

  // ---- Convert + write half A to LDS ------------------------------------
  if (a0_ok) {
#pragma unroll
    for (int j = 0; j < 4; ++j) {
      u32x4 wv;
#pragma unroll
      for (int p = 0; p < 4; ++p)
        wv[p] = pk2(va0[2 * p][j], va0[2 * p + 1][j]);
      *reinterpret_cast<u32x4*>(&xs[(ulb << 2) + j][uc0]) = wv;
    }
  } else {
#pragma unroll
    for (int j = 0; j < 4; ++j) {
      const int gl = a0_gl0 + j;
      u32x4 wv;
#pragma unroll
      for (int p = 0; p < 4; ++p) {
        float lo = 0.f, hi = 0.f;
        if (gl >= 0 && gl < L_IN) {
          lo = xn[(size_t)(uc0 + 2 * p)     * L_IN + gl];
          hi = xn[(size_t)(uc0 + 2 * p + 1) * L_IN + gl];
        }
        wv[p] = pk2(lo, hi);
      }
      *reinterpret_cast<u32x4*>(&xs[(ulb << 2) + j][uc0]) = wv;
    }
  }
  if (have1) {
#pragma unroll
    for (int j = 0; j < 4; ++j) {
      u32x4 wv;
#pragma unroll
      for (int p = 0; p < 4; ++p)
        wv[p] = pk2(va1[2 * p][j], va1[2 * p + 1][j]);
      *reinterpret_cast<u32x4*>(&xs[128 + (ulb << 2) + j][uc0]) = wv;
    }
  }
  __syncthreads();

  // ---- Compute ----------------------------------------------------------
  const int wave = tid >> 6;
  const int lane = tid & 63;
  const int col  = lane & 15;
  const int quad = lane >> 4;

  const unsigned short* wbase = w2 + (((wave << 4) + col) << 6) + (quad << 3);
  const int obase = (wave << 4) + (quad << 2);
  float bv[4];
#pragma unroll
  for (int reg = 0; reg < 4; ++reg) bv[reg] = bias[obase + reg];

  f32x4 acc[8];
#pragma unroll
  for (int lt = 0; lt < 8; ++lt) acc[lt] = (f32x4){0.f, 0.f, 0.f, 0.f};

  // -- half A: out cols l0 .. l0+127; LDS rows r = col + t + 4 + lt*16 ----
  for (int t = 0; t < KTAP; ++t) {
    bf16x8 a[2];
#pragma unroll
    for (int k = 0; k < 2; ++k)
      a[k] = *reinterpret_cast<const bf16x8*>(wbase + (t << 12) + (k << 5));
#pragma unroll
    for (int k = 0; k < 2; ++k) {
#pragma unroll
      for (int lt = 0; lt < 8; ++lt) {
        const int r = col + t + 4 + (lt << 4);
        const bf16x8 b = *reinterpret_cast<const bf16x8*>(&xs[r][(k << 5) + (quad << 3)]);
        acc[lt] = __builtin_amdgcn_mfma_f32_16x16x32_bf16(a[k], b, acc[lt], 0, 0, 0);
      }
    }
  }

  // ---- Convert + write half B to LDS (rows 144..271 — disjoint from the
  //      rows 4..139 compute-A just read, so no barrier needed above) -----
  if (b_ok) {
#pragma unroll
    for (int j = 0; j < 4; ++j) {
      u32x4 wv;
#pragma unroll
      for (int p = 0; p < 4; ++p)
        wv[p] = pk2(vb[2 * p][j], vb[2 * p + 1][j]);
      *reinterpret_cast<u32x4*>(&xs[144 + (ulb << 2) + j][uc0]) = wv;
    }
  } else {
#pragma unroll
    for (int j = 0; j < 4; ++j) {
      const int gl = b_gl0 + j;
      u32x4 wv;
#pragma unroll
      for (int p = 0; p < 4; ++p) {
        float lo = 0.f, hi = 0.f;
        if (gl < L_IN) {
          lo = xn[(size_t)(uc0 + 2 * p)     * L_IN + gl];
          hi = xn[(size_t)(uc0 + 2 * p + 1) * L_IN + gl];
        }
        wv[p] = pk2(lo, hi);
      }
      *reinterpret_cast<u32x4*>(&xs[144 + (ulb << 2) + j][uc0]) = wv;
    }
  }
  __syncthreads();

  // ---- store half A (global writes fly under compute-B) -----------------
#pragma unroll
  for (int lt = 0; lt < 8; ++lt) {
    const int l = l0 + (lt << 4) + col;
#pragma unroll
    for (int reg = 0; reg < 4; ++reg)
      out[((size_t)(n * O_OUT + obase + reg) << 14) + l] = acc[lt][reg] + bv[reg];
  }

  // -- half B: out cols l0+128 .. l0+255; rows r = 128 + col + t + 4 + lt*16
#pragma unroll
  for (int lt = 0; lt < 8; ++lt) acc[lt] = (f32x4){0.f, 0.f, 0.f, 0.f};

  for (int t = 0; t < KTAP; ++t) {
    bf16x8 a[2];
#pragma unroll
    for (int k = 0; k < 2; ++k)
      a[k] = *reinterpret_cast<const bf16x8*>(wbase + (t << 12) + (k << 5));
#pragma unroll
    for (int k = 0; k < 2; ++k) {
#pragma unroll
      for (int lt = 0; lt < 8; ++lt) {
        const int r = 128 + col + t + 4 + (lt << 4);
        const bf16x8 b = *reinterpret_cast<const bf16x8*>(&xs[r][(k << 5) + (quad << 3)]);
        acc[lt] = __builtin_amdgcn_mfma_f32_16x16x32_bf16(a[k], b, acc[lt], 0, 0, 0);
      }
    }
  }

  // ---- store half B -----------------------------------------------------
#pragma unroll
  for (int lt = 0; lt < 8; ++lt) {
    const int l = l0 + 128 + (lt << 4) + col;
#pragma unroll
    for (int reg = 0; reg < 4; ++reg)
      out[((size_t)(n * O_OUT + obase + reg) << 14) + l] = acc[lt][reg] + bv[reg];
  }
}

extern "C" void kernel_launch(void* const* d_in, const int* in_sizes, int n_in,
                              void* d_out, int out_size, void* d_ws, size_t ws_size,
                              hipStream_t stream) {
  const float*    x    = (const float*)d_in[0];
  const float*    w    = (const float*)d_in[1];
  const float*    bias = (const float*)d_in[2];
  float*          out  = (float*)d_out;
  unsigned short* w2   = (unsigned short*)d_ws;   // 73728 B scratch (bf16 weights)

  // 1) rearrange + downcast + pre-scale weights into d_ws (runs every call)
  w_rearrange<<<(KTAP * O_OUT * C_IN + 255) / 256, 256, 0, stream>>>(w, w2);

  // 2) fused conv-as-GEMM: 8 n * 64 L-tiles = 512 blocks
  qconv_kernel<<<8 * (L_IN / LTILE), 256, 0, stream>>>(x, w2, bias, out);

  // 3) MEASUREMENT: identical second dispatch (idempotent). Marginal cost on
  //    dur_us = qconv body time (L3-warm). Remove after this round.
  qconv_kernel<<<8 * (L_IN / LTILE), 256, 0, stream>>>(x, w2, bias, out);
}

// Round 9
// 104.312 us; speedup vs baseline: 1.1353x; 1.1353x over previous
//
#include <hip/hip_runtime.h>
#include <hip/hip_bf16.h>

// QConv1d: x (8,64,16384) f32, w (64,64,9) f32, bias (64) f32
// out (8,64,16384) f32 = conv1d(x, w, pad=4) * 0.125 + bias
// Strategy: cast to bf16 (weights pre-scaled by 0.125 — exact, power of two),
// MFMA f32_16x16x32_bf16, fp32 accumulate, fp32 out.
// Round-13 (resubmit — round-8 bench was an infra failure, kernel never ran):
// halve LDS read traffic. Round-12's double-dispatch measured the
// warm body at 20.4 µs ≈ SUM of pipe times (LDS port 11.5 + stores 5.3 +
// reads 2 + MFMA/VALU 2.7) — phases barely overlap at 8 waves/CU, and
// adding TLP regresses (R1/R4). Biggest term: LDS reads. Round-7's T14
// split made each B-frag feed only 1 MFMA (1152 b128/block); this round
// restores round-0's m-pairing INSIDE the T14 skeleton: wave layout
// 2(O-half) x 2(L-quarter), each wave computes 32 O x 64 L per phase, so
// each B-read feeds acc[0] and acc[1] -> 576 b128/block (5.8 µs port time).
// T14 invariant kept: phase-A rows = wq*64+col+t+4+lt*16 ∈ [4,139] ⊂ region
// A; half-B LDS write needs no barrier before it; store-A overlaps
// compute-B. VGPR peak ~170 -> 2 blocks/CU preserved.
#define C_IN    64
#define L_IN    16384
#define O_OUT   64
#define KTAP    9
#define LTILE   256
#define ROWS    272      // LTILE + 16 halo rows (global l in [l0-8, l0+264))
#define RSTRIDE 72       // 64 + 8 pad (multiple of 8 -> 16B-aligned b128 rows)

typedef short          bf16x8 __attribute__((ext_vector_type(8)));   // MFMA A/B frag
typedef unsigned int   u32x4  __attribute__((ext_vector_type(4)));
typedef float          f32x4  __attribute__((ext_vector_type(4)));   // MFMA C/D frag

static __device__ __forceinline__ unsigned short f2bf(float f) {
  __hip_bfloat16 h = __float2bfloat16(f);   // round-to-nearest
  return __builtin_bit_cast(unsigned short, h);
}

// pack two floats -> one u32 of two bf16 (lo in low 16 bits)
static __device__ __forceinline__ unsigned int pk2(float lo, float hi) {
  return (unsigned int)f2bf(lo) | ((unsigned int)f2bf(hi) << 16);
}

// ---------------------------------------------------------------------------
// Pre-kernel: w[o][c][t] fp32 (stride-9 taps) -> W2[t][o][c] bf16 (c contig),
// pre-scaled by 0.125 (exact: power-of-two only touches the exponent).
// ---------------------------------------------------------------------------
__global__ void w_rearrange(const float* __restrict__ w,
                            unsigned short* __restrict__ w2) {
    int i = blockIdx.x * 256 + threadIdx.x;       // i = t*4096 + o*64 + c
    if (i >= KTAP * O_OUT * C_IN) return;
    int t  = i >> 12;
    int oc = i & 4095;                            // o*64 + c
    w2[i] = f2bf(w[oc * KTAP + t] * 0.125f);
}

// ---------------------------------------------------------------------------
// Main kernel: one block = one n, one 256-wide L tile, all 64 outputs.
// 4 waves in 2(O-half) x 2(L-quarter); per phase each wave computes
// 32 O x 64 L with B-frag reuse across the two 16-O subtiles.
// ---------------------------------------------------------------------------
__global__ __launch_bounds__(256) void qconv_kernel(
    const float* __restrict__ x,
    const unsigned short* __restrict__ w2,    // bf16 bits, pre-scaled
    const float* __restrict__ bias,
    float* __restrict__ out) {

  __shared__ __align__(16) unsigned short xs[ROWS][RSTRIDE];  // bf16 x tile, [l][c]

  const int tid = threadIdx.x;
  const int n   = blockIdx.x >> 6;
  const int l0  = (blockIdx.x & 63) << 8;      // tile base along L
  const float* xn = x + (size_t)n * C_IN * L_IN;

  // ---- Issue phase: all global loads for this tile ----------------------
  // Staging unit = 8 channels x 4 l (8x f32x4 loads). A region rows [0,144)
  // = 288 units (tid<32 take a second unit); B region rows [144,272) = 256
  // units, one per thread, held in registers through compute-A.
  const int ucb = tid & 7;            // channel block (c0 = ucb*8)
  const int ulb = tid >> 3;           // l block within region (0..31)
  const int uc0 = ucb << 3;

  // A unit 0 (rows ulb*4 .. +3)
  const int a0_gl0 = l0 - 8 + (ulb << 2);
  const bool a0_ok = (a0_gl0 >= 0) && (a0_gl0 + 4 <= L_IN);
  f32x4 va0[8];
  if (a0_ok) {
#pragma unroll
    for (int i = 0; i < 8; ++i)
      va0[i] = *reinterpret_cast<const f32x4*>(xn + (size_t)(uc0 + i) * L_IN + a0_gl0);
  }
  // A unit 1 (tid < 32): rows 128 + (tid>>3)*4 .. +3  — always in-bounds
  const bool have1 = (tid < 32);
  const int a1_gl0 = l0 - 8 + ((32 + ulb) << 2);   // only meaningful for tid<32
  f32x4 va1[8];
  if (have1) {
#pragma unroll
    for (int i = 0; i < 8; ++i)
      va1[i] = *reinterpret_cast<const f32x4*>(xn + (size_t)(uc0 + i) * L_IN + a1_gl0);
  }
  // B unit: rows 144 + ulb*4 .. +3 (gl0 >= 136 >= 0 always)
  const int b_gl0 = l0 + 136 + (ulb << 2);
  const bool b_ok = (b_gl0 + 4 <= L_IN);
  f32x4 vb[8];
  if (b_ok) {
#pragma unroll
    for (int i = 0; i < 8; ++i)
      vb[i] = *reinterpret_cast<const f32x4*>(xn + (size_t)(uc0 + i) * L_IN + b_gl0);
  }

  // ---- Convert + write half A to LDS ------------------------------------
  if (a0_ok) {
#pragma unroll
    for (int j = 0; j < 4; ++j) {
      u32x4 wv;
#pragma unroll
      for (int p = 0; p < 4; ++p)
        wv[p] = pk2(va0[2 * p][j], va0[2 * p + 1][j]);
      *reinterpret_cast<u32x4*>(&xs[(ulb << 2) + j][uc0]) = wv;
    }
  } else {
#pragma unroll
    for (int j = 0; j < 4; ++j) {
      const int gl = a0_gl0 + j;
      u32x4 wv;
#pragma unroll
      for (int p = 0; p < 4; ++p) {
        float lo = 0.f, hi = 0.f;
        if (gl >= 0 && gl < L_IN) {
          lo = xn[(size_t)(uc0 + 2 * p)     * L_IN + gl];
          hi = xn[(size_t)(uc0 + 2 * p + 1) * L_IN + gl];
        }
        wv[p] = pk2(lo, hi);
      }
      *reinterpret_cast<u32x4*>(&xs[(ulb << 2) + j][uc0]) = wv;
    }
  }
  if (have1) {
#pragma unroll
    for (int j = 0; j < 4; ++j) {
      u32x4 wv;
#pragma unroll
      for (int p = 0; p < 4; ++p)
        wv[p] = pk2(va1[2 * p][j], va1[2 * p + 1][j]);
      *reinterpret_cast<u32x4*>(&xs[128 + (ulb << 2) + j][uc0]) = wv;
    }
  }
  __syncthreads();

  // ---- Compute ----------------------------------------------------------
  const int wave = tid >> 6;
  const int lane = tid & 63;
  const int wr   = wave >> 1;       // O half: o in [32*wr, 32*wr+32)
  const int wq   = wave & 1;        // L quarter within each 128-half
  const int col  = lane & 15;
  const int quad = lane >> 4;

  const int obase = (wr << 5) + (quad << 2);
  float bv[2][4];
#pragma unroll
  for (int m = 0; m < 2; ++m)
#pragma unroll
    for (int reg = 0; reg < 4; ++reg) bv[m][reg] = bias[obase + (m << 4) + reg];

  f32x4 acc[2][4];
#pragma unroll
  for (int m = 0; m < 2; ++m)
#pragma unroll
    for (int lt = 0; lt < 4; ++lt) acc[m][lt] = (f32x4){0.f, 0.f, 0.f, 0.f};

  // -- phase A: out cols l0 + wq*64 + [0,64); LDS rows wq*64+col+t+4+lt*16
  //    (max 139 < 144: stays inside region A — T14 invariant) -------------
  const int rbaseA = (wq << 6) + col + 4;
  for (int t = 0; t < KTAP; ++t) {
    bf16x8 a[2][2];
#pragma unroll
    for (int m = 0; m < 2; ++m)
#pragma unroll
      for (int k = 0; k < 2; ++k)
        a[m][k] = *reinterpret_cast<const bf16x8*>(
            w2 + (t << 12) + (((wr << 5) + (m << 4) + col) << 6) + (k << 5) + (quad << 3));
#pragma unroll
    for (int k = 0; k < 2; ++k) {
#pragma unroll
      for (int lt = 0; lt < 4; ++lt) {
        const int r = rbaseA + t + (lt << 4);
        const bf16x8 b = *reinterpret_cast<const bf16x8*>(&xs[r][(k << 5) + (quad << 3)]);
        acc[0][lt] = __builtin_amdgcn_mfma_f32_16x16x32_bf16(a[0][k], b, acc[0][lt], 0, 0, 0);
        acc[1][lt] = __builtin_amdgcn_mfma_f32_16x16x32_bf16(a[1][k], b, acc[1][lt], 0, 0, 0);
      }
    }
  }

  // ---- Convert + write half B to LDS (rows 144..271 — disjoint from the
  //      rows 4..139 compute-A just read, so no barrier needed above) -----
  if (b_ok) {
#pragma unroll
    for (int j = 0; j < 4; ++j) {
      u32x4 wv;
#pragma unroll
      for (int p = 0; p < 4; ++p)
        wv[p] = pk2(vb[2 * p][j], vb[2 * p + 1][j]);
      *reinterpret_cast<u32x4*>(&xs[144 + (ulb << 2) + j][uc0]) = wv;
    }
  } else {
#pragma unroll
    for (int j = 0; j < 4; ++j) {
      const int gl = b_gl0 + j;
      u32x4 wv;
#pragma unroll
      for (int p = 0; p < 4; ++p) {
        float lo = 0.f, hi = 0.f;
        if (gl < L_IN) {
          lo = xn[(size_t)(uc0 + 2 * p)     * L_IN + gl];
          hi = xn[(size_t)(uc0 + 2 * p + 1) * L_IN + gl];
        }
        wv[p] = pk2(lo, hi);
      }
      *reinterpret_cast<u32x4*>(&xs[144 + (ulb << 2) + j][uc0]) = wv;
    }
  }
  __syncthreads();

  // ---- store phase A (global writes fly under compute-B) ----------------
#pragma unroll
  for (int m = 0; m < 2; ++m) {
#pragma unroll
    for (int lt = 0; lt < 4; ++lt) {
      const int l = l0 + (wq << 6) + (lt << 4) + col;
#pragma unroll
      for (int reg = 0; reg < 4; ++reg)
        out[((size_t)(n * O_OUT + obase + (m << 4) + reg) << 14) + l] =
            acc[m][lt][reg] + bv[m][reg];
    }
  }

  // -- phase B: out cols l0 + 128 + wq*64 + [0,64); rows += 128 -----------
#pragma unroll
  for (int m = 0; m < 2; ++m)
#pragma unroll
    for (int lt = 0; lt < 4; ++lt) acc[m][lt] = (f32x4){0.f, 0.f, 0.f, 0.f};

  for (int t = 0; t < KTAP; ++t) {
    bf16x8 a[2][2];
#pragma unroll
    for (int m = 0; m < 2; ++m)
#pragma unroll
      for (int k = 0; k < 2; ++k)
        a[m][k] = *reinterpret_cast<const bf16x8*>(
            w2 + (t << 12) + (((wr << 5) + (m << 4) + col) << 6) + (k << 5) + (quad << 3));
#pragma unroll
    for (int k = 0; k < 2; ++k) {
#pragma unroll
      for (int lt = 0; lt < 4; ++lt) {
        const int r = 128 + rbaseA + t + (lt << 4);
        const bf16x8 b = *reinterpret_cast<const bf16x8*>(&xs[r][(k << 5) + (quad << 3)]);
        acc[0][lt] = __builtin_amdgcn_mfma_f32_16x16x32_bf16(a[0][k], b, acc[0][lt], 0, 0, 0);
        acc[1][lt] = __builtin_amdgcn_mfma_f32_16x16x32_bf16(a[1][k], b, acc[1][lt], 0, 0, 0);
      }
    }
  }

  // ---- store phase B ----------------------------------------------------
#pragma unroll
  for (int m = 0; m < 2; ++m) {
#pragma unroll
    for (int lt = 0; lt < 4; ++lt) {
      const int l = l0 + 128 + (wq << 6) + (lt << 4) + col;
#pragma unroll
      for (int reg = 0; reg < 4; ++reg)
        out[((size_t)(n * O_OUT + obase + (m << 4) + reg) << 14) + l] =
            acc[m][lt][reg] + bv[m][reg];
    }
  }
}

extern "C" void kernel_launch(void* const* d_in, const int* in_sizes, int n_in,
                              void* d_out, int out_size, void* d_ws, size_t ws_size,
                              hipStream_t stream) {
  const float*    x    = (const float*)d_in[0];
  const float*    w    = (const float*)d_in[1];
  const float*    bias = (const float*)d_in[2];
  float*          out  = (float*)d_out;
  unsigned short* w2   = (unsigned short*)d_ws;   // 73728 B scratch (bf16 weights)

  // 1) rearrange + downcast + pre-scale weights into d_ws (runs every call)
  w_rearrange<<<(KTAP * O_OUT * C_IN + 255) / 256, 256, 0, stream>>>(w, w2);

  // 2) fused conv-as-GEMM: 8 n * 64 L-tiles = 512 blocks
  qconv_kernel<<<8 * (L_IN / LTILE), 256, 0, stream>>>(x, w2, bias, out);
}

// Round 10
// 97.466 us; speedup vs baseline: 1.2151x; 1.0702x over previous
//
#include <hip/hip_runtime.h>
#include <hip/hip_bf16.h>

// QConv1d: x (8,64,16384) f32, w (64,64,9) f32, bias (64) f32
// out (8,64,16384) f32 = conv1d(x, w, pad=4) * 0.125 + bias
// Strategy: cast to bf16 (weights pre-scaled by 0.125 — exact, power of two),
// MFMA f32_16x16x32_bf16, fp32 accumulate, fp32 out.
// Round-14: hoist A-frags out of the MFMA loops. Evidence chain:
//   R12 double-dispatch: warm body = 20.4 µs (~2x pipe floor).
//   R13 (m-pairing): halved ds_reads but DOUBLED inner-loop w2 loads ->
//     +6 µs. R2 doubled ds_reads vs R0 -> neutral. So LDS BW is irrelevant;
//     inner-loop GLOBAL (L2-latency) loads are the sensitive term — with the
//     grid pinning 2 blocks/CU = 2 waves/SIMD there's no TLP to hide them.
//   Grid-pinned residency also means VGPR is free up to 256.
// Change vs round-7/R2 (measured best, 98.0): load the 18 16B A-frags ONCE
// into afr[] (72 VGPR), issued right after the x staging loads (latency
// hides under pack/write VALU); both phase loops become pure ds_read+MFMA.
// Everything else byte-identical to R2.
#define C_IN    64
#define L_IN    16384
#define O_OUT   64
#define KTAP    9
#define LTILE   256
#define ROWS    272      // LTILE + 16 halo rows (global l in [l0-8, l0+264))
#define RSTRIDE 72       // 64 + 8 pad (multiple of 8 -> 16B-aligned b128 rows)

typedef short          bf16x8 __attribute__((ext_vector_type(8)));   // MFMA A/B frag
typedef unsigned int   u32x4  __attribute__((ext_vector_type(4)));
typedef float          f32x4  __attribute__((ext_vector_type(4)));   // MFMA C/D frag

static __device__ __forceinline__ unsigned short f2bf(float f) {
  __hip_bfloat16 h = __float2bfloat16(f);   // round-to-nearest
  return __builtin_bit_cast(unsigned short, h);
}

// pack two floats -> one u32 of two bf16 (lo in low 16 bits)
static __device__ __forceinline__ unsigned int pk2(float lo, float hi) {
  return (unsigned int)f2bf(lo) | ((unsigned int)f2bf(hi) << 16);
}

// ---------------------------------------------------------------------------
// Pre-kernel: w[o][c][t] fp32 (stride-9 taps) -> W2[t][o][c] bf16 (c contig),
// pre-scaled by 0.125 (exact: power-of-two only touches the exponent).
// ---------------------------------------------------------------------------
__global__ void w_rearrange(const float* __restrict__ w,
                            unsigned short* __restrict__ w2) {
    int i = blockIdx.x * 256 + threadIdx.x;       // i = t*4096 + o*64 + c
    if (i >= KTAP * O_OUT * C_IN) return;
    int t  = i >> 12;
    int oc = i & 4095;                            // o*64 + c
    w2[i] = f2bf(w[oc * KTAP + t] * 0.125f);
}

// ---------------------------------------------------------------------------
// Main kernel: one block = one n, one 256-wide L tile, all 64 outputs.
// 4 waves, each owning 16 O rows; the two 128-wide L halves are computed
// sequentially with memory traffic overlapped against MFMA.
// ---------------------------------------------------------------------------
__global__ __launch_bounds__(256) void qconv_kernel(
    const float* __restrict__ x,
    const unsigned short* __restrict__ w2,    // bf16 bits, pre-scaled
    const float* __restrict__ bias,
    float* __restrict__ out) {

  __shared__ __align__(16) unsigned short xs[ROWS][RSTRIDE];  // bf16 x tile, [l][c]

  const int tid = threadIdx.x;
  const int n   = blockIdx.x >> 6;
  const int l0  = (blockIdx.x & 63) << 8;      // tile base along L
  const float* xn = x + (size_t)n * C_IN * L_IN;

  // ---- Issue phase: all global x loads for this tile --------------------
  const int ucb = tid & 7;            // channel block (c0 = ucb*8)
  const int ulb = tid >> 3;           // l block within region (0..31)
  const int uc0 = ucb << 3;

  // A unit 0 (rows ulb*4 .. +3)
  const int a0_gl0 = l0 - 8 + (ulb << 2);
  const bool a0_ok = (a0_gl0 >= 0) && (a0_gl0 + 4 <= L_IN);
  f32x4 va0[8];
  if (a0_ok) {
#pragma unroll
    for (int i = 0; i < 8; ++i)
      va0[i] = *reinterpret_cast<const f32x4*>(xn + (size_t)(uc0 + i) * L_IN + a0_gl0);
  }
  // A unit 1 (tid < 32): rows 128 + (tid>>3)*4 .. +3  — always in-bounds
  const bool have1 = (tid < 32);
  const int a1_gl0 = l0 - 8 + ((32 + ulb) << 2);   // only meaningful for tid<32
  f32x4 va1[8];
  if (have1) {
#pragma unroll
    for (int i = 0; i < 8; ++i)
      va1[i] = *reinterpret_cast<const f32x4*>(xn + (size_t)(uc0 + i) * L_IN + a1_gl0);
  }
  // B unit: rows 144 + ulb*4 .. +3 (gl0 >= 136 >= 0 always)
  const int b_gl0 = l0 + 136 + (ulb << 2);
  const bool b_ok = (b_gl0 + 4 <= L_IN);
  f32x4 vb[8];
  if (b_ok) {
#pragma unroll
    for (int i = 0; i < 8; ++i)
      vb[i] = *reinterpret_cast<const f32x4*>(xn + (size_t)(uc0 + i) * L_IN + b_gl0);
  }

  // ---- Hoisted A-frags: the 18 16B w2 fragments used by BOTH phases -----
  // (w2 is 72 KB, L2-resident; issued here so the latency hides under the
  // pack/write VALU below. +72 VGPR — free: grid pins 2 waves/SIMD, so
  // anything <=256 VGPR costs nothing.)
  const int wave = tid >> 6;
  const int lane = tid & 63;
  const int col  = lane & 15;
  const int quad = lane >> 4;
  const unsigned short* wbase = w2 + (((wave << 4) + col) << 6) + (quad << 3);

  bf16x8 afr[2 * KTAP];
#pragma unroll
  for (int t = 0; t < KTAP; ++t)
#pragma unroll
    for (int k = 0; k < 2; ++k)
      afr[(t << 1) + k] =
          *reinterpret_cast<const bf16x8*>(wbase + (t << 12) + (k << 5));

  // ---- Convert + write half A to LDS ------------------------------------
  if (a0_ok) {
#pragma unroll
    for (int j = 0; j < 4; ++j) {
      u32x4 wv;
#pragma unroll
      for (int p = 0; p < 4; ++p)
        wv[p] = pk2(va0[2 * p][j], va0[2 * p + 1][j]);
      *reinterpret_cast<u32x4*>(&xs[(ulb << 2) + j][uc0]) = wv;
    }
  } else {
#pragma unroll
    for (int j = 0; j < 4; ++j) {
      const int gl = a0_gl0 + j;
      u32x4 wv;
#pragma unroll
      for (int p = 0; p < 4; ++p) {
        float lo = 0.f, hi = 0.f;
        if (gl >= 0 && gl < L_IN) {
          lo = xn[(size_t)(uc0 + 2 * p)     * L_IN + gl];
          hi = xn[(size_t)(uc0 + 2 * p + 1) * L_IN + gl];
        }
        wv[p] = pk2(lo, hi);
      }
      *reinterpret_cast<u32x4*>(&xs[(ulb << 2) + j][uc0]) = wv;
    }
  }
  if (have1) {
#pragma unroll
    for (int j = 0; j < 4; ++j) {
      u32x4 wv;
#pragma unroll
      for (int p = 0; p < 4; ++p)
        wv[p] = pk2(va1[2 * p][j], va1[2 * p + 1][j]);
      *reinterpret_cast<u32x4*>(&xs[128 + (ulb << 2) + j][uc0]) = wv;
    }
  }
  __syncthreads();

  // ---- Compute ----------------------------------------------------------
  const int obase = (wave << 4) + (quad << 2);
  float bv[4];
#pragma unroll
  for (int reg = 0; reg < 4; ++reg) bv[reg] = bias[obase + reg];

  f32x4 acc[8];
#pragma unroll
  for (int lt = 0; lt < 8; ++lt) acc[lt] = (f32x4){0.f, 0.f, 0.f, 0.f};

  // -- half A: out cols l0 .. l0+127; LDS rows r = col + t + 4 + lt*16 ----
#pragma unroll
  for (int t = 0; t < KTAP; ++t) {
#pragma unroll
    for (int k = 0; k < 2; ++k) {
      const bf16x8 a = afr[(t << 1) + k];
#pragma unroll
      for (int lt = 0; lt < 8; ++lt) {
        const int r = col + t + 4 + (lt << 4);
        const bf16x8 b = *reinterpret_cast<const bf16x8*>(&xs[r][(k << 5) + (quad << 3)]);
        acc[lt] = __builtin_amdgcn_mfma_f32_16x16x32_bf16(a, b, acc[lt], 0, 0, 0);
      }
    }
  }

  // ---- Convert + write half B to LDS (rows 144..271 — disjoint from the
  //      rows 4..139 compute-A just read, so no barrier needed above) -----
  if (b_ok) {
#pragma unroll
    for (int j = 0; j < 4; ++j) {
      u32x4 wv;
#pragma unroll
      for (int p = 0; p < 4; ++p)
        wv[p] = pk2(vb[2 * p][j], vb[2 * p + 1][j]);
      *reinterpret_cast<u32x4*>(&xs[144 + (ulb << 2) + j][uc0]) = wv;
    }
  } else {
#pragma unroll
    for (int j = 0; j < 4; ++j) {
      const int gl = b_gl0 + j;
      u32x4 wv;
#pragma unroll
      for (int p = 0; p < 4; ++p) {
        float lo = 0.f, hi = 0.f;
        if (gl < L_IN) {
          lo = xn[(size_t)(uc0 + 2 * p)     * L_IN + gl];
          hi = xn[(size_t)(uc0 + 2 * p + 1) * L_IN + gl];
        }
        wv[p] = pk2(lo, hi);
      }
      *reinterpret_cast<u32x4*>(&xs[144 + (ulb << 2) + j][uc0]) = wv;
    }
  }
  __syncthreads();

  // ---- store half A (global writes fly under compute-B) -----------------
#pragma unroll
  for (int lt = 0; lt < 8; ++lt) {
    const int l = l0 + (lt << 4) + col;
#pragma unroll
    for (int reg = 0; reg < 4; ++reg)
      out[((size_t)(n * O_OUT + obase + reg) << 14) + l] = acc[lt][reg] + bv[reg];
  }

  // -- half B: out cols l0+128 .. l0+255; rows r = 128 + col + t + 4 + lt*16
#pragma unroll
  for (int lt = 0; lt < 8; ++lt) acc[lt] = (f32x4){0.f, 0.f, 0.f, 0.f};

#pragma unroll
  for (int t = 0; t < KTAP; ++t) {
#pragma unroll
    for (int k = 0; k < 2; ++k) {
      const bf16x8 a = afr[(t << 1) + k];
#pragma unroll
      for (int lt = 0; lt < 8; ++lt) {
        const int r = 128 + col + t + 4 + (lt << 4);
        const bf16x8 b = *reinterpret_cast<const bf16x8*>(&xs[r][(k << 5) + (quad << 3)]);
        acc[lt] = __builtin_amdgcn_mfma_f32_16x16x32_bf16(a, b, acc[lt], 0, 0, 0);
      }
    }
  }

  // ---- store half B -----------------------------------------------------
#pragma unroll
  for (int lt = 0; lt < 8; ++lt) {
    const int l = l0 + 128 + (lt << 4) + col;
#pragma unroll
    for (int reg = 0; reg < 4; ++reg)
      out[((size_t)(n * O_OUT + obase + reg) << 14) + l] = acc[lt][reg] + bv[reg];
  }
}

extern "C" void kernel_launch(void* const* d_in, const int* in_sizes, int n_in,
                              void* d_out, int out_size, void* d_ws, size_t ws_size,
                              hipStream_t stream) {
  const float*    x    = (const float*)d_in[0];
  const float*    w    = (const float*)d_in[1];
  const float*    bias = (const float*)d_in[2];
  float*          out  = (float*)d_out;
  unsigned short* w2   = (unsigned short*)d_ws;   // 73728 B scratch (bf16 weights)

  // 1) rearrange + downcast + pre-scale weights into d_ws (runs every call)
  w_rearrange<<<(KTAP * O_OUT * C_IN + 255) / 256, 256, 0, stream>>>(w, w2);

  // 2) fused conv-as-GEMM: 8 n * 64 L-tiles = 512 blocks
  qconv_kernel<<<8 * (L_IN / LTILE), 256, 0, stream>>>(x, w2, bias, out);
}